// Round 7
// baseline (247.742 us; speedup 1.0000x reference)
//
#include <hip/hip_runtime.h>

namespace {

constexpr int   kT = 512, kC = 512, kL = 128, kBlank = 511;
constexpr int   kQ  = 128;   // rows per quarter
constexpr int   kNQ = 4;
constexpr int   kW  = 136;   // compact width: col0=blank, 1..128=labels[0..127], pad
constexpr float kNeg = -1e30f, kEps = 1e-7f, kLn2 = 0.6931471805599453f;

typedef float __attribute__((address_space(1))) f32g;
typedef float __attribute__((address_space(3))) f32l;

__device__ __forceinline__ void glds4(const float* g, float* l) {
    __builtin_amdgcn_global_load_lds((const f32g*)g, (f32l*)l, 4, 0, 0);
}
__device__ __forceinline__ float rlane(float x, int l) {
    return __int_as_float(__builtin_amdgcn_readlane(__float_as_int(x), l));
}
__device__ __forceinline__ float bperm(int a, float x) {
    return __int_as_float(__builtin_amdgcn_ds_bpermute(a, __float_as_int(x)));
}

__global__ __launch_bounds__(128, 1) void ctc_fwd_kernel(
        const int* __restrict__ labels,
        const float* __restrict__ y_pred,
        float* __restrict__ out) {
    __shared__ __align__(16) float lp[2][kQ][kW];   // 136 KiB double buffer

    const int tid  = (int)threadIdx.x;
    const int lane = tid & 63;
    const int wv   = tid >> 6;           // wave 0 = consumer, wave 1 = producer
    const int b    = (int)blockIdx.x;
    const float* yp  = y_pred + (size_t)b * kT * kC;
    const int*   lab = labels + b * kL;

    // ---- producer constants: per-lane gather classes ----
    int clsA = 0, clsB = 0, clsC = 0;
    if (wv == 1) {
        clsA = (lane == 0) ? kBlank : lab[lane - 1];   // cols 0..63
        clsB = lab[63 + lane];                         // cols 64..127
        clsC = (lane == 0) ? lab[127] : kBlank;        // cols 128..135 (128 real)
    }

    // ---- consumer constants: state s = lane + 64k ----
    int  col[4] = {0, 0, 0, 0};
    bool skp[4] = {false, false, false, false};
    float a[4] = {kNeg, kNeg, kNeg, kNeg}, a256 = kNeg;
    if (wv == 0) {
#pragma unroll
        for (int k = 0; k < 4; ++k) {
            const int s = lane + 64 * k;
            if (s & 1) {
                col[k] = ((s - 1) >> 1) + 1;
                skp[k] = (s >= 3) && (lab[(s - 1) >> 1] != lab[(s - 3) >> 1]);
            }
        }
    }
    const int addr1 = (lane - 1) << 2;   // bpermute byte addrs (r2/r3-proven)
    const int addr2 = (lane - 2) << 2;

    // ---- prologue: stage quarter 0 ----
    if (wv == 1) {
        for (int r = 0; r < kQ; ++r) {
            const float* row = yp + (size_t)r * kC;
            glds4(row + clsA, &lp[0][r][0]);
            glds4(row + clsB, &lp[0][r][64]);
            if (lane < 8) glds4(row + clsC, &lp[0][r][128]);
        }
    }
    __syncthreads();

    for (int q = 0; q < kNQ; ++q) {
        if (wv == 1) {
            // ---- producer: stage quarter q+1 into the other buffer ----
            if (q < kNQ - 1) {
                float (*buf)[kW] = lp[(q + 1) & 1];
                for (int r = 0; r < kQ; ++r) {
                    const float* row = yp + (size_t)((q + 1) * kQ + r) * kC;
                    glds4(row + clsA, &buf[r][0]);
                    glds4(row + clsB, &buf[r][64]);
                    if (lane < 8) glds4(row + clsC, &buf[r][128]);
                }
            }
        } else {
            // ---- consumer: 128 recurrence steps from buffer q&1 ----
            float (*buf)[kW] = lp[q & 1];
            int rs = 0;
            if (q == 0) {
                const float r0 = buf[0][col[0]];   // lane0: blank, lane1: labels[0]
                a[0] = (lane < 2) ? __log2f(r0 + kEps) : kNeg;
                rs = 1;
            }
            float raw[4];
#pragma unroll
            for (int k = 0; k < 4; ++k) raw[k] = buf[rs][col[k]];
            for (int r = rs; r < kQ; ++r) {
                float nraw[4] = {raw[0], raw[1], raw[2], raw[3]};
                if (r + 1 < kQ) {
#pragma unroll
                    for (int k = 0; k < 4; ++k) nraw[k] = buf[r + 1][col[k]];
                }
                float lp2[4];
#pragma unroll
                for (int k = 0; k < 4; ++k) lp2[k] = __log2f(raw[k] + kEps);
                float an[4];
#pragma unroll
                for (int k = 0; k < 4; ++k) {
                    const float s1 = bperm(addr1, a[k]);
                    const float s2 = bperm(addr2, a[k]);
                    float am1, am2;
                    if (k == 0) {
                        am1 = (lane == 0) ? kNeg : s1;
                        am2 = (lane <= 1) ? kNeg : s2;
                    } else {
                        const float e63 = rlane(a[k - 1], 63);
                        const float e62 = rlane(a[k - 1], 62);
                        am1 = (lane == 0) ? e63 : s1;
                        am2 = (lane == 0) ? e62 : ((lane == 1) ? e63 : s2);
                    }
                    const float a3v = skp[k] ? am2 : kNeg;
                    const float m   = fmaxf(fmaxf(a[k], am1), a3v);
                    const float sum = exp2f(a[k] - m) + exp2f(am1 - m) + exp2f(a3v - m);
                    an[k] = m + __log2f(sum) + lp2[k];
                }
                {   // state 256 (scalar tail state)
                    const float a255 = rlane(a[3], 63);
                    const float lpb  = rlane(lp2[0], 0);   // blank lp of row r
                    const float m2   = fmaxf(a256, a255);
                    a256 = m2 + __log2f(exp2f(a256 - m2) + exp2f(a255 - m2)) + lpb;
                }
#pragma unroll
                for (int k = 0; k < 4; ++k) { a[k] = an[k]; raw[k] = nraw[k]; }
            }
        }
        __syncthreads();
    }

    // ---- loss = -ln2 * logaddexp2(alpha[256], alpha[255]) ----
    if (wv == 0) {
        const float a255 = rlane(a[3], 63);
        const float m    = fmaxf(a256, a255);
        const float loss = -kLn2 * (m + __log2f(exp2f(a256 - m) + exp2f(a255 - m)));
        if (lane == 0) out[b] = loss;
    }
}

} // namespace

extern "C" void kernel_launch(void* const* d_in, const int* in_sizes, int n_in,
                              void* d_out, int out_size, void* d_ws, size_t ws_size,
                              hipStream_t stream) {
    const int*   labels = (const int*)d_in[0];   // y_true [256,128] int32
    const float* y_pred = (const float*)d_in[1]; // y_pred [256,512,512] f32
    float*       out    = (float*)d_out;         // loss [256,1] f32
    (void)in_sizes; (void)n_in; (void)d_ws; (void)ws_size;
    hipLaunchKernelGGL(ctc_fwd_kernel, dim3(out_size), dim3(128), 0, stream,
                       labels, y_pred, out);
}

// Round 8
// 188.255 us; speedup vs baseline: 1.3160x; 1.3160x over previous
//
#include <hip/hip_runtime.h>

namespace {

constexpr int   kT = 512, kC = 512, kL = 128, kBlank = 511;
constexpr int   kQ  = 128;   // rows per quarter
constexpr int   kNQ = 4;
constexpr int   kW  = 136;   // compact width: col0=blank, 1..128=labels[0..127], pad
constexpr float kNeg = -1e30f, kEps = 1e-7f, kLn2 = 0.6931471805599453f;

typedef float __attribute__((address_space(1))) f32g;
typedef float __attribute__((address_space(3))) f32l;

__device__ __forceinline__ void glds4(const float* g, float* l) {
    __builtin_amdgcn_global_load_lds((const f32g*)g, (f32l*)l, 4, 0, 0);
}
__device__ __forceinline__ float rlane(float x, int l) {
    return __int_as_float(__builtin_amdgcn_readlane(__float_as_int(x), l));
}
__device__ __forceinline__ float bperm(int a, float x) {
    return __int_as_float(__builtin_amdgcn_ds_bpermute(a, __float_as_int(x)));
}
// Single-instruction transcendentals (v_exp_f32 / v_log_f32, base-2).
// Proven bit-adequate in round 3 (passed, absmax 0.0).
__device__ __forceinline__ float EXP2(float x) { return __builtin_amdgcn_exp2f(x); }
__device__ __forceinline__ float LOG2(float x) { return __builtin_amdgcn_logf(x); }

__global__ __launch_bounds__(128, 1) void ctc_fwd_kernel(
        const int* __restrict__ labels,
        const float* __restrict__ y_pred,
        float* __restrict__ out) {
    __shared__ __align__(16) float lp[2][kQ][kW];   // 136 KiB double buffer

    const int tid  = (int)threadIdx.x;
    const int lane = tid & 63;
    const int wv   = tid >> 6;           // wave 0 = consumer, wave 1 = producer
    const int b    = (int)blockIdx.x;
    const float* yp  = y_pred + (size_t)b * kT * kC;
    const int*   lab = labels + b * kL;

    // ---- producer constants: per-lane gather classes ----
    int clsA = 0, clsB = 0, clsC = 0;
    if (wv == 1) {
        clsA = (lane == 0) ? kBlank : lab[lane - 1];   // cols 0..63
        clsB = lab[63 + lane];                         // cols 64..127
        clsC = (lane == 0) ? lab[127] : kBlank;        // cols 128..135 (128 real)
    }

    // ---- consumer constants: state s = lane + 64k ----
    int  col[4] = {0, 0, 0, 0};
    bool skp[4] = {false, false, false, false};
    float a[4] = {kNeg, kNeg, kNeg, kNeg}, a256 = kNeg;
    if (wv == 0) {
#pragma unroll
        for (int k = 0; k < 4; ++k) {
            const int s = lane + 64 * k;
            if (s & 1) {
                col[k] = ((s - 1) >> 1) + 1;
                skp[k] = (s >= 3) && (lab[(s - 1) >> 1] != lab[(s - 3) >> 1]);
            }
        }
    }
    const int addr1 = (lane - 1) << 2;   // bpermute byte addrs (r2/r3-proven)
    const int addr2 = (lane - 2) << 2;

    // ---- prologue: stage quarter 0 ----
    if (wv == 1) {
        for (int r = 0; r < kQ; ++r) {
            const float* row = yp + (size_t)r * kC;
            glds4(row + clsA, &lp[0][r][0]);
            glds4(row + clsB, &lp[0][r][64]);
            if (lane < 8) glds4(row + clsC, &lp[0][r][128]);
        }
    }
    __syncthreads();

    for (int q = 0; q < kNQ; ++q) {
        if (wv == 1) {
            // ---- producer: stage quarter q+1 into the other buffer ----
            if (q < kNQ - 1) {
                float (*buf)[kW] = lp[(q + 1) & 1];
                for (int r = 0; r < kQ; ++r) {
                    const float* row = yp + (size_t)((q + 1) * kQ + r) * kC;
                    glds4(row + clsA, &buf[r][0]);
                    glds4(row + clsB, &buf[r][64]);
                    if (lane < 8) glds4(row + clsC, &buf[r][128]);
                }
            }
        } else {
            // ---- consumer: 128 recurrence steps from buffer q&1 ----
            float (*buf)[kW] = lp[q & 1];
            int rs = 0;
            if (q == 0) {
                const float r0 = buf[0][col[0]];   // lane0: blank, lane1: labels[0]
                a[0] = (lane < 2) ? LOG2(r0 + kEps) : kNeg;
                rs = 1;
            }
            float raw[4];
#pragma unroll
            for (int k = 0; k < 4; ++k) raw[k] = buf[rs][col[k]];
            for (int r = rs; r < kQ; ++r) {
                float nraw[4] = {raw[0], raw[1], raw[2], raw[3]};
                if (r + 1 < kQ) {
#pragma unroll
                    for (int k = 0; k < 4; ++k) nraw[k] = buf[r + 1][col[k]];
                }
                float lp2[4];
#pragma unroll
                for (int k = 0; k < 4; ++k) lp2[k] = LOG2(raw[k] + kEps);
                float an[4];
#pragma unroll
                for (int k = 0; k < 4; ++k) {
                    const float s1 = bperm(addr1, a[k]);
                    const float s2 = bperm(addr2, a[k]);
                    float am1, am2;
                    if (k == 0) {
                        am1 = (lane == 0) ? kNeg : s1;
                        am2 = (lane <= 1) ? kNeg : s2;
                    } else {
                        const float e63 = rlane(a[k - 1], 63);
                        const float e62 = rlane(a[k - 1], 62);
                        am1 = (lane == 0) ? e63 : s1;
                        am2 = (lane == 0) ? e62 : ((lane == 1) ? e63 : s2);
                    }
                    const float a3v = skp[k] ? am2 : kNeg;
                    const float m   = fmaxf(fmaxf(a[k], am1), a3v);
                    const float sum = EXP2(a[k] - m) + EXP2(am1 - m) + EXP2(a3v - m);
                    an[k] = m + LOG2(sum) + lp2[k];
                }
                {   // state 256 (scalar tail state)
                    const float a255 = rlane(a[3], 63);
                    const float lpb  = rlane(lp2[0], 0);   // blank lp of row r
                    const float m2   = fmaxf(a256, a255);
                    a256 = m2 + LOG2(EXP2(a256 - m2) + EXP2(a255 - m2)) + lpb;
                }
#pragma unroll
                for (int k = 0; k < 4; ++k) { a[k] = an[k]; raw[k] = nraw[k]; }
            }
        }
        __syncthreads();
    }

    // ---- loss = -ln2 * logaddexp2(alpha[256], alpha[255]) ----
    if (wv == 0) {
        const float a255 = rlane(a[3], 63);
        const float m    = fmaxf(a256, a255);
        const float loss = -kLn2 * (m + LOG2(EXP2(a256 - m) + EXP2(a255 - m)));
        if (lane == 0) out[b] = loss;
    }
}

} // namespace

extern "C" void kernel_launch(void* const* d_in, const int* in_sizes, int n_in,
                              void* d_out, int out_size, void* d_ws, size_t ws_size,
                              hipStream_t stream) {
    const int*   labels = (const int*)d_in[0];   // y_true [256,128] int32
    const float* y_pred = (const float*)d_in[1]; // y_pred [256,512,512] f32
    float*       out    = (float*)d_out;         // loss [256,1] f32
    (void)in_sizes; (void)n_in; (void)d_ws; (void)ws_size;
    hipLaunchKernelGGL(ctc_fwd_kernel, dim3(out_size), dim3(128), 0, stream,
                       labels, y_pred, out);
}

// Round 9
// 111.422 us; speedup vs baseline: 2.2235x; 1.6896x over previous
//
#include <hip/hip_runtime.h>

namespace {

constexpr int   kT = 512, kC = 512, kL = 128, kBlank = 511;
constexpr int   kCH  = 16;         // rows per chunk
constexpr int   kNCH = kT / kCH;   // 32 chunks
constexpr float kEps = 1e-7f, kLn2 = 0.6931471805599453f;

typedef float __attribute__((address_space(1))) f32g;
typedef float __attribute__((address_space(3))) f32l;

// Coalesced width-16 global->LDS: 64 lanes x 16B = 1KB (half a row).
__device__ __forceinline__ void glds16(const float* g, float* l) {
    __builtin_amdgcn_global_load_lds((const f32g*)g, (f32l*)l, 16, 0, 0);
}
__device__ __forceinline__ float rlane(float x, int l) {
    return __int_as_float(__builtin_amdgcn_readlane(__float_as_int(x), l));
}
__device__ __forceinline__ float bperm(int a, float x) {
    return __int_as_float(__builtin_amdgcn_ds_bpermute(a, __float_as_int(x)));
}
__device__ __forceinline__ float LOG2(float x) { return __builtin_amdgcn_logf(x); }

__global__ __launch_bounds__(128, 1) void ctc_fwd_kernel(
        const int* __restrict__ labels,
        const float* __restrict__ y_pred,
        float* __restrict__ out) {
    __shared__ __align__(16) float buf[2][kCH][kC];   // 64 KiB double buffer

    const int tid  = (int)threadIdx.x;
    const int lane = tid & 63;
    const int wv   = tid >> 6;           // wave 0 = consumer, wave 1 = producer
    const int b    = (int)blockIdx.x;
    const float* yp  = y_pred + (size_t)b * kT * kC;
    const int*   lab = labels + b * kL;

    // ---- consumer constants: state s = lane + 64k; class ids into full row --
    int  cls[4];
    bool skp[4];
#pragma unroll
    for (int k = 0; k < 4; ++k) {
        const int s = lane + 64 * k;
        if (s & 1) {
            cls[k] = lab[(s - 1) >> 1];
            skp[k] = (s >= 3) && (lab[(s - 1) >> 1] != lab[(s - 3) >> 1]);
        } else { cls[k] = kBlank; skp[k] = false; }
    }
    const int addr1 = (lane - 1) << 2;   // bpermute byte addrs (r2..r8-proven)
    const int addr2 = (lane - 2) << 2;

    // ---- prologue: producer stages chunk 0 (coalesced full rows) ----
    if (wv == 1) {
        for (int r = 0; r < kCH; ++r) {
            const float* row = yp + (size_t)r * kC;
            glds16(row + lane * 4,       &buf[0][r][0]);
            glds16(row + 256 + lane * 4, &buf[0][r][256]);
        }
    }
    __syncthreads();

    // ---- linear-domain scaled forward state ----
    float a[4] = {0.f, 0.f, 0.f, 0.f}, a256 = 0.f, etot = 0.f;

    for (int c = 0; c < kNCH; ++c) {
        if (wv == 1) {
            // ---- producer: stage chunk c+1 (pure coalesced streaming) ----
            if (c + 1 < kNCH) {
                float (*bf)[kC] = buf[(c + 1) & 1];
                for (int r = 0; r < kCH; ++r) {
                    const float* row = yp + (size_t)((c + 1) * kCH + r) * kC;
                    glds16(row + lane * 4,       &bf[r][0]);
                    glds16(row + 256 + lane * 4, &bf[r][256]);
                }
            }
        } else {
            // ---- consumer: 16 recurrence steps from chunk c ----
            float (*bf)[kC] = buf[c & 1];
            for (int r = 0; r < kCH; ++r) {
                float p[4];
#pragma unroll
                for (int k = 0; k < 4; ++k) p[k] = bf[r][cls[k]] + kEps;
                if (c == 0 && r == 0) {
                    // t=0 init: alpha0[0]=p(blank), alpha0[1]=p(label0)
                    a[0] = (lane < 2) ? p[0] : 0.f;
                } else {
                    float an[4];
#pragma unroll
                    for (int k = 0; k < 4; ++k) {
                        const float s1 = bperm(addr1, a[k]);
                        const float s2 = bperm(addr2, a[k]);
                        float am1, am2;
                        if (k == 0) {
                            am1 = (lane == 0) ? 0.f : s1;
                            am2 = (lane <= 1) ? 0.f : s2;
                        } else {
                            const float e63 = rlane(a[k - 1], 63);
                            const float e62 = rlane(a[k - 1], 62);
                            am1 = (lane == 0) ? e63 : s1;
                            am2 = (lane == 0) ? e62 : ((lane == 1) ? e63 : s2);
                        }
                        const float a3v = skp[k] ? am2 : 0.f;
                        an[k] = (a[k] + am1 + a3v) * p[k];
                    }
                    {   // state 256 (blank tail, scalar)
                        const float a255 = rlane(a[3], 63);
                        const float pb   = rlane(p[0], 0);   // blank prob+eps
                        a256 = (a256 + a255) * pb;
                    }
#pragma unroll
                    for (int k = 0; k < 4; ++k) a[k] = an[k];
                }
            }
            // ---- lossless power-of-2 renorm every 2 chunks (32 steps) ----
            if (c & 1) {
                float m = fmaxf(fmaxf(a[0], a[1]), fmaxf(a[2], a[3]));
#pragma unroll
                for (int i = 1; i < 64; i <<= 1) m = fmaxf(m, __shfl_xor(m, i));
                m = fmaxf(m, a256);
                const int ex = (__float_as_int(m) >> 23) & 0xFF;
                if (ex > 1) {
                    const float sc = __int_as_float((254 - ex) << 23);  // 2^(127-ex)
                    a[0] *= sc; a[1] *= sc; a[2] *= sc; a[3] *= sc; a256 *= sc;
                    etot += (float)(ex - 127);
                }
            }
        }
        __syncthreads();
    }

    // ---- loss = -ln2 * (log2(alpha255 + alpha256) + etot) ----
    if (wv == 0) {
        const float a255 = rlane(a[3], 63);
        const float s    = a255 + a256;
        const float loss = -kLn2 * (LOG2(s) + etot);
        if (lane == 0) out[b] = loss;
    }
}

} // namespace

extern "C" void kernel_launch(void* const* d_in, const int* in_sizes, int n_in,
                              void* d_out, int out_size, void* d_ws, size_t ws_size,
                              hipStream_t stream) {
    const int*   labels = (const int*)d_in[0];   // y_true [256,128] int32
    const float* y_pred = (const float*)d_in[1]; // y_pred [256,512,512] f32
    float*       out    = (float*)d_out;         // loss [256,1] f32
    (void)in_sizes; (void)n_in; (void)d_ws; (void)ws_size;
    hipLaunchKernelGGL(ctc_fwd_kernel, dim3(out_size), dim3(128), 0, stream,
                       labels, y_pred, out);
}